// Round 10
// baseline (1851.397 us; speedup 1.0000x reference)
//
#include <hip/hip_runtime.h>
#include <hip/hip_bf16.h>

// EntropyResidualBlock: y1 = prelu(maskconv(x,w1)+b1); y2 = prelu(maskconv(y1,w2)+b2); out = y2 + x
// 13 live taps. Implicit GEMM with mfma_f32_32x32x16_bf16.
//   conv1: D[p][o] = sum X[p+d(t)][i]*W1[t][i][o]  (A=X,B=W);  conv2: D[o][p] (A=W,B=Y).
// Layouts: X/Y packed [n][kc=24 x 16ch][h+4][w+4][16] bf16 (halo-padded);
//          W packed [t][kc][o][16] bf16 (masked).
// Round-10: m201-style double-barrier 2-step phases. 13 phases/ic:
//   {BAR; setprio1; read xaB; 8 MFMA(stepA); wb refill; read next xaA;
//    8 MFMA(stepB); wb refill; setprio0; BAR}
// 16-MFMA fenced clusters; ds_reads hidden under the first octet; memory window
// strictly between clusters. Registers unchanged (xa ring-2, wb ring-2,
// consume-then-prefetch, cross-ic wb continuity). Staging via global_load_lds
// at ic top (verified); __syncthreads at ic boundary (verified). Epilogue,
// halo-zero, repack, prepack unchanged. Xc in d_out; ws: [Y][Wp1][Wp2].

#define C_CH 384
#define HH   256
#define WWD  512
#define NN   2
#define NKC  24                    // 16-channel chunks
#define PR   260
#define PC   516
#define ICS16 (PR * PC * 16)       // shorts per (n,kc) plane = 2,146,560
#define TCOLS 144
#define PLANE_SH (4 * TCOLS * 16)  // 9216 shorts per hf sub-plane in LDS
#define TSH (2 * PLANE_SH)         // 18432 shorts = 36,864 B per buffer

typedef __attribute__((ext_vector_type(8)))  short short8;
typedef __attribute__((ext_vector_type(16))) float f32x16;

typedef const __attribute__((address_space(1))) void* gas_t;
typedef __attribute__((address_space(3))) void* las_t;

__device__ inline unsigned short f2bf(float f) {
    union { float f; unsigned int u; } v; v.f = f;
    unsigned int r = v.u + 0x7FFFu + ((v.u >> 16) & 1u);
    return (unsigned short)(r >> 16);
}

// ---------------- weights -> bf16 wp[t][kc][o][16], masked ----------------
__global__ __launch_bounds__(256) void k_prepack(const float* __restrict__ w1, const float* __restrict__ w2,
                                                 unsigned short* __restrict__ wp1, unsigned short* __restrict__ wp2) {
    int idx = blockIdx.x * 256 + threadIdx.x;
    const int TOT = 13 * NKC * C_CH * 16;
    if (idx >= TOT) return;
    int iq = idx & 15;
    int o  = (idx >> 4) % C_CH;
    int kc = (idx / (16 * C_CH)) % NKC;
    int t  = idx / (16 * C_CH * NKC);
    int i  = kc * 16 + iq;
    int kh = t < 5 ? 0 : (t < 10 ? 1 : 2);
    int kw = t < 5 ? t : (t < 10 ? t - 5 : t - 10);
    bool keep = (t != 12) || ((i / 24) <= (o / 24));
    int src = ((o * C_CH + i) * 5 + kh) * 5 + kw;
    wp1[idx] = keep ? f2bf(w1[src]) : (unsigned short)0;
    wp2[idx] = keep ? f2bf(w2[src]) : (unsigned short)0;
}

// ---------------- zero the halo borders of both packed buffers ----------------
__global__ __launch_bounds__(256) void k_zero_halo(unsigned short* __restrict__ a, unsigned short* __restrict__ b) {
    int plane = blockIdx.x;            // 0..47 (n*NKC+kc)
    const short8 z = (short8){0,0,0,0,0,0,0,0};
    for (int bi = 0; bi < 2; ++bi) {
        unsigned short* p = (bi ? b : a) + (size_t)plane * ICS16;
        // top rows 0,1 + bottom rows 258,259: 4 rows x 516 cols x 2 q = 4128 short8
        for (int i = threadIdx.x; i < 4128; i += 256) {
            int r4 = i / 1032;
            int rem = i - r4 * 1032;
            int row = r4 < 2 ? r4 : 254 + r4;
            *(short8*)&p[row * (PC * 16) + rem * 8] = z;
        }
        // side cols 0,1,514,515 for rows 2..257: 256 rows x 8 short8
        for (int i = threadIdx.x; i < 2048; i += 256) {
            int row = 2 + (i >> 3);
            int j = i & 7;
            int col = (j < 4) ? (j >> 1) : (512 + (j >> 1));
            int q = j & 1;
            *(short8*)&p[(row * PC + col) * 16 + q * 8] = z;
        }
    }
}

// ---------------- x NCHW fp32 -> padded 16ch-chunked bf16 ----------------
__global__ __launch_bounds__(256) void k_repack_x(const float* __restrict__ x, unsigned short* __restrict__ xc) {
    int bid = blockIdx.x;              // 4096 blocks: 64 w x 384 c for one (n,h)
    int w0 = (bid & 7) << 6;
    int h  = (bid >> 3) & 255;
    int n  = bid >> 11;
    int wi = threadIdx.x & 63;
    int cq = threadIdx.x >> 6;         // 0..3 (8 channels each)
    int w  = w0 + wi;
    int inb = n * C_CH * HH * WWD + h * WWD + w;
    for (int cc = 0; cc < 12; ++cc) {
        int c0 = cc * 32 + cq * 8;
        short8 outv;
        #pragma unroll
        for (int k = 0; k < 8; ++k) {
            float f = x[inb + (c0 + k) * (HH * WWD)];
            outv[k] = (short)f2bf(f);
        }
        int kc = cc * 2 + (cq >> 1);
        int oidx = (n * NKC + kc) * ICS16 + ((h + 2) * PC + (w + 2)) * 16 + (cq & 1) * 8;
        *(short8*)&xc[oidx] = outv;
    }
}

// ---------------- masked conv via 32x32x16 MFMA ----------------
// grid 3072; 256 threads / 4 waves (wr = h-row 0/1, wc = o-half).
template<int SECOND>
__global__ __launch_bounds__(256, 2) void k_conv(const unsigned short* __restrict__ in,   // packed
                                                 const unsigned short* __restrict__ wp,
                                                 const float* __restrict__ bias,
                                                 const float* __restrict__ alpha,
                                                 const float* __restrict__ xres,
                                                 void* __restrict__ outp) {
    __shared__ __align__(16) unsigned short Xs[2][TSH];   // 2 x 36,864 B

    // ob slow within XCD chunk: 3 ob-blocks of one tile run consecutively on one XCD
    int bid0 = blockIdx.x;
    int xcd = bid0 & 7;
    int j0  = bid0 >> 3;
    int tile = xcd * 128 + j0 / 3;
    int ob   = j0 % 3;
    int n    = tile >> 9;
    int hp   = (tile >> 2) & 127;
    int wseg = tile & 3;
    int w0 = wseg << 7, o0 = ob << 7, h0 = hp << 1;

    int tid = threadIdx.x;
    int lane = tid & 63;
    int wv = tid >> 6;
    int wr = wv >> 1, wc = wv & 1;
    int lo5 = lane & 31, hi = lane >> 5;

    // staging: 36 wave-issues per buffer, 9 per wave; per-lane global offsets
    int goff[9];
    #pragma unroll
    for (int it = 0; it < 9; ++it) {
        int k = wv * 9 + it;
        int plane = k / 18;
        int s = (k % 18) * 64 + lane;
        int r = s / 288;
        int rem = s - r * 288;
        int col = rem >> 1, h16 = rem & 1;
        goff[it] = plane * ICS16 + ((h0 + r) * PC + (w0 + col)) * 16 + h16 * 8;
    }

    const int KH[13] = {0,0,0,0,0,1,1,1,1,1,2,2,2};
    const int KW[13] = {0,1,2,3,4,0,1,2,3,4,0,1,2};

    f32x16 acc[4][2];
    #pragma unroll
    for (int pt = 0; pt < 4; ++pt)
        #pragma unroll
        for (int ot = 0; ot < 2; ++ot)
            #pragma unroll
            for (int r = 0; r < 16; ++r) acc[pt][ot][r] = 0.f;

    const unsigned short* gbase_n = in + (size_t)n * NKC * ICS16;

#define LOAD_XA(dst, u) do {                                              \
        int t_ = (u) >> 1, hf_ = (u) & 1;                                 \
        int so_ = hf_ * PLANE_SH + (wr + KH[t_]) * (TCOLS * 16)           \
                + (lo5 + KW[t_]) * 16 + hi * 8;                           \
        _Pragma("unroll")                                                 \
        for (int pt_ = 0; pt_ < 4; ++pt_)                                 \
            (dst)[pt_] = *(const short8*)&xs[so_ + pt_ * 512];            \
    } while (0)

#define LOAD_WB(dst, icc, u) do {                                         \
        int t_ = (u) >> 1, hf_ = (u) & 1;                                 \
        const unsigned short* wb_ = wp +                                  \
            (size_t)((t_ * NKC + (icc) * 2 + hf_) * C_CH + o0 + wc * 64) * 16; \
        _Pragma("unroll")                                                 \
        for (int ot_ = 0; ot_ < 2; ++ot_)                                 \
            (dst)[ot_] = *(const short8*)&wb_[(ot_ * 32 + lo5) * 16 + hi * 8]; \
    } while (0)

#define OCTET(xv, wv_) do {                                               \
        _Pragma("unroll")                                                 \
        for (int pt = 0; pt < 4; ++pt)                                    \
            _Pragma("unroll")                                             \
            for (int ot = 0; ot < 2; ++ot) {                              \
                if (SECOND)                                               \
                    acc[pt][ot] = __builtin_amdgcn_mfma_f32_32x32x16_bf16( \
                        (wv_)[ot], (xv)[pt], acc[pt][ot], 0, 0, 0);        \
                else                                                      \
                    acc[pt][ot] = __builtin_amdgcn_mfma_f32_32x32x16_bf16( \
                        (xv)[pt], (wv_)[ot], acc[pt][ot], 0, 0, 0);        \
            }                                                             \
    } while (0)

    short8 wb[2][2];
    // wb for (ic=0, u=0,1) issued FIRST: ahead of all staging in the vmcnt queue
    LOAD_WB(wb[0], 0, 0);
    LOAD_WB(wb[1], 0, 1);

    // prologue: stage ic=0 into buf 0
    #pragma unroll
    for (int it = 0; it < 9; ++it)
        __builtin_amdgcn_global_load_lds((gas_t)(gbase_n + goff[it]),
                                         (las_t)&Xs[0][(wv * 9 + it) * 512], 16, 0, 0);
    __syncthreads();

    for (int ic = 0; ic < 12; ++ic) {
        int buf = ic & 1;
        const unsigned short* xs = &Xs[buf][0];
        // stage next ic into other buffer (wb for steps 0,1 already issued earlier)
        if (ic < 11) {
            const unsigned short* gb = gbase_n + (size_t)(ic + 1) * 2 * ICS16;
            #pragma unroll
            for (int it = 0; it < 9; ++it)
                __builtin_amdgcn_global_load_lds((gas_t)(gb + goff[it]),
                                                 (las_t)&Xs[buf ^ 1][(wv * 9 + it) * 512], 16, 0, 0);
        }

        short8 xa[2][4];
        LOAD_XA(xa[0], 0);

        // 13 double-barrier phases of 2 steps (uA=2k even slot, uB=2k+1 odd slot).
        #pragma unroll
        for (int k = 0; k < 13; ++k) {
            int uA = 2 * k, uB = 2 * k + 1;
            __builtin_amdgcn_s_barrier();
            __builtin_amdgcn_s_setprio(1);
            // xaB read here: first octet's ~258cy covers its latency
            LOAD_XA(xa[1], uB);
            OCTET(xa[0], wb[0]);
            // refill even wb slot (steps 24 -> next ic's u=0)
            if (uA + 2 < 26)      LOAD_WB(wb[0], ic, uA + 2);
            else if (ic < 11)     LOAD_WB(wb[0], ic + 1, 0);
            // read next phase's even-slot fragments (second octet covers latency)
            if (uB + 1 < 26)      LOAD_XA(xa[0], uB + 1);
            OCTET(xa[1], wb[1]);
            // refill odd wb slot (step 25 -> next ic's u=1)
            if (uB + 2 < 26)      LOAD_WB(wb[1], ic, uB + 2);
            else if (ic < 11)     LOAD_WB(wb[1], ic + 1, 1);
            __builtin_amdgcn_s_setprio(0);
            __builtin_amdgcn_s_barrier();
        }
        __syncthreads();
    }
#undef LOAD_XA
#undef LOAD_WB
#undef OCTET

    int h = h0 + wr;
    if (!SECOND) {
        // D[p][o]: p = pt*32 + (reg&3)+8*(reg>>2)+4*hi ; o = o0+wc*64+ot*32+lo5
        unsigned short* y = (unsigned short*)outp;
        #pragma unroll
        for (int ot = 0; ot < 2; ++ot) {
            int o = o0 + wc * 64 + ot * 32 + lo5;
            float bo = bias[o], ao = alpha[o];
            int kc = o >> 4;
            int o15 = o & 15;
            size_t base = (size_t)(n * NKC + kc) * ICS16 + ((h + 2) * PC + (w0 + 2)) * 16 + o15;
            #pragma unroll
            for (int pt = 0; pt < 4; ++pt) {
                #pragma unroll
                for (int reg = 0; reg < 16; ++reg) {
                    int p = pt * 32 + (reg & 3) + 8 * (reg >> 2) + 4 * hi;
                    float v = acc[pt][ot][reg] + bo;
                    v = v >= 0.f ? v : ao * v;
                    y[base + (size_t)p * 16] = f2bf(v);
                }
            }
        }
    } else {
        // D[o][p]: o = o0+wc*64+ot*32+(reg&3)+8*(reg>>2)+4*hi ; w = w0+pt*32+lo5
        float* outf = (float*)outp;
        #pragma unroll
        for (int ot = 0; ot < 2; ++ot) {
            #pragma unroll
            for (int reg = 0; reg < 16; ++reg) {
                int o = o0 + wc * 64 + ot * 32 + (reg & 3) + 8 * (reg >> 2) + 4 * hi;
                float bo = bias[o], ao = alpha[o];
                #pragma unroll
                for (int pt = 0; pt < 4; ++pt) {
                    int w = w0 + pt * 32 + lo5;
                    float v = acc[pt][ot][reg] + bo;
                    v = v >= 0.f ? v : ao * v;
                    size_t idx = (size_t)((n * C_CH + o) * HH + h) * WWD + w;
                    outf[idx] = v + xres[idx];
                }
            }
        }
    }
}

extern "C" void kernel_launch(void* const* d_in, const int* in_sizes, int n_in,
                              void* d_out, int out_size, void* d_ws, size_t ws_size,
                              hipStream_t stream) {
    const float* x  = (const float*)d_in[0];
    const float* w1 = (const float*)d_in[1];
    const float* b1 = (const float*)d_in[2];
    const float* a1 = (const float*)d_in[3];
    const float* w2 = (const float*)d_in[4];
    const float* b2 = (const float*)d_in[5];
    const float* a2 = (const float*)d_in[6];

    const size_t PLANE_SHORTS = (size_t)NN * NKC * ICS16;       // 103,034,880 shorts
    unsigned short* xc  = (unsigned short*)d_out;               // 206,069,760 B scratch in d_out
    unsigned short* yb  = (unsigned short*)d_ws;                // 206,069,760 B
    unsigned short* wp1 = yb + PLANE_SHORTS;                    // 3,833,856 B
    unsigned short* wp2 = wp1 + 13 * NKC * C_CH * 16;           // 3,833,856 B

    k_prepack<<<(13 * NKC * C_CH * 16 + 255) / 256, 256, 0, stream>>>(w1, w2, wp1, wp2);
    k_zero_halo<<<NN * NKC, 256, 0, stream>>>(xc, yb);
    k_repack_x<<<NN * HH * (WWD / 64), 256, 0, stream>>>(x, xc);
    k_conv<0><<<3072, 256, 0, stream>>>(xc, wp1, b1, a1, nullptr, (void*)yb);
    k_conv<1><<<3072, 256, 0, stream>>>(yb, wp2, b2, a2, x, (void*)d_out);
}

// Round 11
// 1801.000 us; speedup vs baseline: 1.0280x; 1.0280x over previous
//
#include <hip/hip_runtime.h>
#include <hip/hip_bf16.h>

// EntropyResidualBlock: y1 = prelu(maskconv(x,w1)+b1); y2 = prelu(maskconv(y1,w2)+b2); out = y2 + x
// 13 live taps. Implicit GEMM with mfma_f32_32x32x16_bf16.
//   conv1: D[p][o] = sum X[p+d(t)][i]*W1[t][i][o]  (A=X,B=W);  conv2: D[o][p] (A=W,B=Y).
// Layouts: X/Y packed [n][kc=24 x 16ch][h+4][w+4][16] bf16 (halo-padded);
//          W packed [t][kc][o][16] bf16 (masked).
// Round-11: R9 body (best verified, 1808us) + strength-reduced addressing:
//   - xa: single per-ic base (xsp + xlane), every ds_read_b128 uses a
//     compile-time byte immediate (hf*PLANE_SH + kh*2304 + kw*16 + pt*512).
//   - wb: running scalar short-offset, bumped by compile-time TSTRIDE per
//     refill (cross-ic adjust -12*TSTRIDE+12288); loads = base + lane + imm.
//   Cuts ~70 VALU-cycles/step of recomputed address arithmetic that stole
//   issue slots from the co-resident wave's MFMA stream.
// Per-step s_barrier (R9), setprio around octet, wb ring-2 w/ cross-ic
// continuity, staging at ic top, __syncthreads at ic boundary — all verified.

#define C_CH 384
#define HH   256
#define WWD  512
#define NN   2
#define NKC  24                    // 16-channel chunks
#define PR   260
#define PC   516
#define ICS16 (PR * PC * 16)       // shorts per (n,kc) plane = 2,146,560
#define TCOLS 144
#define PLANE_SH (4 * TCOLS * 16)  // 9216 shorts per hf sub-plane in LDS
#define TSH (2 * PLANE_SH)         // 18432 shorts = 36,864 B per buffer
#define TSTRIDE (NKC * C_CH * 16)  // 147456 shorts: t -> t+1 in wp
#define ICSTRIDE (2 * C_CH * 16)   // 12288 shorts: ic -> ic+1 (kc += 2)

typedef __attribute__((ext_vector_type(8)))  short short8;
typedef __attribute__((ext_vector_type(16))) float f32x16;

typedef const __attribute__((address_space(1))) void* gas_t;
typedef __attribute__((address_space(3))) void* las_t;

__device__ inline unsigned short f2bf(float f) {
    union { float f; unsigned int u; } v; v.f = f;
    unsigned int r = v.u + 0x7FFFu + ((v.u >> 16) & 1u);
    return (unsigned short)(r >> 16);
}

// ---------------- weights -> bf16 wp[t][kc][o][16], masked ----------------
__global__ __launch_bounds__(256) void k_prepack(const float* __restrict__ w1, const float* __restrict__ w2,
                                                 unsigned short* __restrict__ wp1, unsigned short* __restrict__ wp2) {
    int idx = blockIdx.x * 256 + threadIdx.x;
    const int TOT = 13 * NKC * C_CH * 16;
    if (idx >= TOT) return;
    int iq = idx & 15;
    int o  = (idx >> 4) % C_CH;
    int kc = (idx / (16 * C_CH)) % NKC;
    int t  = idx / (16 * C_CH * NKC);
    int i  = kc * 16 + iq;
    int kh = t < 5 ? 0 : (t < 10 ? 1 : 2);
    int kw = t < 5 ? t : (t < 10 ? t - 5 : t - 10);
    bool keep = (t != 12) || ((i / 24) <= (o / 24));
    int src = ((o * C_CH + i) * 5 + kh) * 5 + kw;
    wp1[idx] = keep ? f2bf(w1[src]) : (unsigned short)0;
    wp2[idx] = keep ? f2bf(w2[src]) : (unsigned short)0;
}

// ---------------- zero the halo borders of both packed buffers ----------------
__global__ __launch_bounds__(256) void k_zero_halo(unsigned short* __restrict__ a, unsigned short* __restrict__ b) {
    int plane = blockIdx.x;            // 0..47 (n*NKC+kc)
    const short8 z = (short8){0,0,0,0,0,0,0,0};
    for (int bi = 0; bi < 2; ++bi) {
        unsigned short* p = (bi ? b : a) + (size_t)plane * ICS16;
        // top rows 0,1 + bottom rows 258,259: 4 rows x 516 cols x 2 q = 4128 short8
        for (int i = threadIdx.x; i < 4128; i += 256) {
            int r4 = i / 1032;
            int rem = i - r4 * 1032;
            int row = r4 < 2 ? r4 : 254 + r4;
            *(short8*)&p[row * (PC * 16) + rem * 8] = z;
        }
        // side cols 0,1,514,515 for rows 2..257: 256 rows x 8 short8
        for (int i = threadIdx.x; i < 2048; i += 256) {
            int row = 2 + (i >> 3);
            int j = i & 7;
            int col = (j < 4) ? (j >> 1) : (512 + (j >> 1));
            int q = j & 1;
            *(short8*)&p[(row * PC + col) * 16 + q * 8] = z;
        }
    }
}

// ---------------- x NCHW fp32 -> padded 16ch-chunked bf16 ----------------
__global__ __launch_bounds__(256) void k_repack_x(const float* __restrict__ x, unsigned short* __restrict__ xc) {
    int bid = blockIdx.x;              // 4096 blocks: 64 w x 384 c for one (n,h)
    int w0 = (bid & 7) << 6;
    int h  = (bid >> 3) & 255;
    int n  = bid >> 11;
    int wi = threadIdx.x & 63;
    int cq = threadIdx.x >> 6;         // 0..3 (8 channels each)
    int w  = w0 + wi;
    int inb = n * C_CH * HH * WWD + h * WWD + w;
    for (int cc = 0; cc < 12; ++cc) {
        int c0 = cc * 32 + cq * 8;
        short8 outv;
        #pragma unroll
        for (int k = 0; k < 8; ++k) {
            float f = x[inb + (c0 + k) * (HH * WWD)];
            outv[k] = (short)f2bf(f);
        }
        int kc = cc * 2 + (cq >> 1);
        int oidx = (n * NKC + kc) * ICS16 + ((h + 2) * PC + (w + 2)) * 16 + (cq & 1) * 8;
        *(short8*)&xc[oidx] = outv;
    }
}

// ---------------- masked conv via 32x32x16 MFMA ----------------
// grid 3072; 256 threads / 4 waves (wr = h-row 0/1, wc = o-half).
template<int SECOND>
__global__ __launch_bounds__(256, 2) void k_conv(const unsigned short* __restrict__ in,   // packed
                                                 const unsigned short* __restrict__ wp,
                                                 const float* __restrict__ bias,
                                                 const float* __restrict__ alpha,
                                                 const float* __restrict__ xres,
                                                 void* __restrict__ outp) {
    __shared__ __align__(16) unsigned short Xs[2][TSH];   // 2 x 36,864 B

    // ob slow within XCD chunk: 3 ob-blocks of one tile run consecutively on one XCD
    int bid0 = blockIdx.x;
    int xcd = bid0 & 7;
    int j0  = bid0 >> 3;
    int tile = xcd * 128 + j0 / 3;
    int ob   = j0 % 3;
    int n    = tile >> 9;
    int hp   = (tile >> 2) & 127;
    int wseg = tile & 3;
    int w0 = wseg << 7, o0 = ob << 7, h0 = hp << 1;

    int tid = threadIdx.x;
    int lane = tid & 63;
    int wv = tid >> 6;
    int wr = wv >> 1, wc = wv & 1;
    int lo5 = lane & 31, hi = lane >> 5;

    // staging: 36 wave-issues per buffer, 9 per wave; per-lane global offsets
    int goff[9];
    #pragma unroll
    for (int it = 0; it < 9; ++it) {
        int k = wv * 9 + it;
        int plane = k / 18;
        int s = (k % 18) * 64 + lane;
        int r = s / 288;
        int rem = s - r * 288;
        int col = rem >> 1, h16 = rem & 1;
        goff[it] = plane * ICS16 + ((h0 + r) * PC + (w0 + col)) * 16 + h16 * 8;
    }

    f32x16 acc[4][2];
    #pragma unroll
    for (int pt = 0; pt < 4; ++pt)
        #pragma unroll
        for (int ot = 0; ot < 2; ++ot)
            #pragma unroll
            for (int r = 0; r < 16; ++r) acc[pt][ot][r] = 0.f;

    const unsigned short* gbase_n = in + (size_t)n * NKC * ICS16;

    // ---- strength-reduced bases ----
    // xa: all ds_reads = (xsp + xlane) + compile-time immediate
    const int xlane = wr * (TCOLS * 16) + lo5 * 16 + hi * 8;
    // wb: base pointer carries the wave-uniform o part + lane part via wlane
    const unsigned short* wpb = wp + (size_t)(o0 + wc * 64) * 16;
    const int wlane = lo5 * 16 + hi * 8;
    int woff0 = 0;            // slot0 scalar offset (shorts): currently (t,kc) of u held
    int woff1 = C_CH * 16;    // slot1: hf=1 -> kc=1

    // compile-time tap tables (folded in unrolled loop)
    const int KH[13] = {0,0,0,0,0,1,1,1,1,1,2,2,2};
    const int KW[13] = {0,1,2,3,4,0,1,2,3,4,0,1,2};

#define LOAD_XA(dst, u) do {                                              \
        const int t_ = (u) >> 1, hf_ = (u) & 1;                           \
        const int c0_ = hf_ * PLANE_SH + KH[t_] * (TCOLS * 16)            \
                      + KW[t_] * 16;                                      \
        _Pragma("unroll")                                                 \
        for (int pt_ = 0; pt_ < 4; ++pt_)                                 \
            (dst)[pt_] = *(const short8*)&xsp[xlane + c0_ + pt_ * 512];   \
    } while (0)

#define LOAD_WB(dst, woff) do {                                           \
        (dst)[0] = *(const short8*)&wpb[(woff) + wlane];                  \
        (dst)[1] = *(const short8*)&wpb[(woff) + wlane + 512];            \
    } while (0)

#define OCTET(xv, wv_) do {                                               \
        _Pragma("unroll")                                                 \
        for (int pt = 0; pt < 4; ++pt)                                    \
            _Pragma("unroll")                                             \
            for (int ot = 0; ot < 2; ++ot) {                              \
                if (SECOND)                                               \
                    acc[pt][ot] = __builtin_amdgcn_mfma_f32_32x32x16_bf16( \
                        (wv_)[ot], (xv)[pt], acc[pt][ot], 0, 0, 0);        \
                else                                                      \
                    acc[pt][ot] = __builtin_amdgcn_mfma_f32_32x32x16_bf16( \
                        (xv)[pt], (wv_)[ot], acc[pt][ot], 0, 0, 0);        \
            }                                                             \
    } while (0)

    short8 wb[2][2];
    // wb for (ic=0, u=0,1) issued FIRST: ahead of all staging in the vmcnt queue
    LOAD_WB(wb[0], woff0);
    LOAD_WB(wb[1], woff1);

    // prologue: stage ic=0 into buf 0
    #pragma unroll
    for (int it = 0; it < 9; ++it)
        __builtin_amdgcn_global_load_lds((gas_t)(gbase_n + goff[it]),
                                         (las_t)&Xs[0][(wv * 9 + it) * 512], 16, 0, 0);
    __syncthreads();

    for (int ic = 0; ic < 12; ++ic) {
        const unsigned short* xsp = &Xs[ic & 1][0];
        // stage next ic into other buffer (wb for steps 0,1 already issued earlier)
        if (ic < 11) {
            const unsigned short* gb = gbase_n + (size_t)(ic + 1) * 2 * ICS16;
            #pragma unroll
            for (int it = 0; it < 9; ++it)
                __builtin_amdgcn_global_load_lds((gas_t)(gb + goff[it]),
                                                 (las_t)&Xs[(ic & 1) ^ 1][(wv * 9 + it) * 512], 16, 0, 0);
        }

        short8 xa[2][4];
        LOAD_XA(xa[0], 0);

        #pragma unroll
        for (int s2 = 0; s2 < 26; ++s2) {
            if (s2 + 1 < 26) LOAD_XA(xa[(s2 + 1) & 1], s2 + 1);
            // schedule-shaping barrier (R9): clusters reads before / MFMAs after,
            // anti-phasing the two co-resident blocks. Guards no data.
            __builtin_amdgcn_s_barrier();
            __builtin_amdgcn_s_setprio(1);
            OCTET(xa[s2 & 1], wb[s2 & 1]);
            __builtin_amdgcn_s_setprio(0);
            // consume-then-prefetch: refill the slot just used with u = s2+2.
            // Offset bump is a compile-time constant add (t+1 => +TSTRIDE;
            // cross-ic at s2=24/25 => -12*TSTRIDE + ICSTRIDE).
            if (s2 + 2 < 26) {
                if ((s2 & 1) == 0) { woff0 += TSTRIDE; LOAD_WB(wb[0], woff0); }
                else               { woff1 += TSTRIDE; LOAD_WB(wb[1], woff1); }
            } else {
                // next ic's u=0 / u=1 (at ic=11 this points at harmless valid
                // memory inside wp's tail region and is never consumed)
                if ((s2 & 1) == 0) { woff0 += ICSTRIDE - 12 * TSTRIDE; LOAD_WB(wb[0], woff0); }
                else               { woff1 += ICSTRIDE - 12 * TSTRIDE; LOAD_WB(wb[1], woff1); }
            }
        }
        __syncthreads();
    }
#undef LOAD_XA
#undef LOAD_WB
#undef OCTET

    int h = h0 + wr;
    if (!SECOND) {
        // D[p][o]: p = pt*32 + (reg&3)+8*(reg>>2)+4*hi ; o = o0+wc*64+ot*32+lo5
        unsigned short* y = (unsigned short*)outp;
        #pragma unroll
        for (int ot = 0; ot < 2; ++ot) {
            int o = o0 + wc * 64 + ot * 32 + lo5;
            float bo = bias[o], ao = alpha[o];
            int kc = o >> 4;
            int o15 = o & 15;
            size_t base = (size_t)(n * NKC + kc) * ICS16 + ((h + 2) * PC + (w0 + 2)) * 16 + o15;
            #pragma unroll
            for (int pt = 0; pt < 4; ++pt) {
                #pragma unroll
                for (int reg = 0; reg < 16; ++reg) {
                    int p = pt * 32 + (reg & 3) + 8 * (reg >> 2) + 4 * hi;
                    float v = acc[pt][ot][reg] + bo;
                    v = v >= 0.f ? v : ao * v;
                    y[base + (size_t)p * 16] = f2bf(v);
                }
            }
        }
    } else {
        // D[o][p]: o = o0+wc*64+ot*32+(reg&3)+8*(reg>>2)+4*hi ; w = w0+pt*32+lo5
        float* outf = (float*)outp;
        #pragma unroll
        for (int ot = 0; ot < 2; ++ot) {
            #pragma unroll
            for (int reg = 0; reg < 16; ++reg) {
                int o = o0 + wc * 64 + ot * 32 + (reg & 3) + 8 * (reg >> 2) + 4 * hi;
                float bo = bias[o], ao = alpha[o];
                #pragma unroll
                for (int pt = 0; pt < 4; ++pt) {
                    int w = w0 + pt * 32 + lo5;
                    float v = acc[pt][ot][reg] + bo;
                    v = v >= 0.f ? v : ao * v;
                    size_t idx = (size_t)((n * C_CH + o) * HH + h) * WWD + w;
                    outf[idx] = v + xres[idx];
                }
            }
        }
    }
}

extern "C" void kernel_launch(void* const* d_in, const int* in_sizes, int n_in,
                              void* d_out, int out_size, void* d_ws, size_t ws_size,
                              hipStream_t stream) {
    const float* x  = (const float*)d_in[0];
    const float* w1 = (const float*)d_in[1];
    const float* b1 = (const float*)d_in[2];
    const float* a1 = (const float*)d_in[3];
    const float* w2 = (const float*)d_in[4];
    const float* b2 = (const float*)d_in[5];
    const float* a2 = (const float*)d_in[6];

    const size_t PLANE_SHORTS = (size_t)NN * NKC * ICS16;       // 103,034,880 shorts
    unsigned short* xc  = (unsigned short*)d_out;               // 206,069,760 B scratch in d_out
    unsigned short* yb  = (unsigned short*)d_ws;                // 206,069,760 B
    unsigned short* wp1 = yb + PLANE_SHORTS;                    // 3,833,856 B
    unsigned short* wp2 = wp1 + 13 * NKC * C_CH * 16;           // 3,833,856 B

    k_prepack<<<(13 * NKC * C_CH * 16 + 255) / 256, 256, 0, stream>>>(w1, w2, wp1, wp2);
    k_zero_halo<<<NN * NKC, 256, 0, stream>>>(xc, yb);
    k_repack_x<<<NN * HH * (WWD / 64), 256, 0, stream>>>(x, xc);
    k_conv<0><<<3072, 256, 0, stream>>>(xc, wp1, b1, a1, nullptr, (void*)yb);
    k_conv<1><<<3072, 256, 0, stream>>>(yb, wp2, b2, a2, x, (void*)d_out);
}